// Round 1
// baseline (254.806 us; speedup 1.0000x reference)
//
#include <hip/hip_runtime.h>
#include <math.h>

#define B_ 256
#define G_ 4000
#define P_ 128
#define D_ 12000
#define H_ 64
#define O_ 16
#define GH_ 128
#define CH_ 8
#define C_ 5
#define K_ 3
#define EPS_ 1e-5f

// ---------------------------------------------------------------------------
// K0: per-pathway compacted list of active genes (gene_mask[g,p] != 0).
// One wave per pathway; ballot-compaction preserves ascending-g order
// (deterministic).
// ---------------------------------------------------------------------------
__global__ __launch_bounds__(64) void k_active(const float* __restrict__ gene_mask,
                                               int* __restrict__ cnt,
                                               int* __restrict__ list) {
  int p = blockIdx.x;       // 128 blocks
  int lane = threadIdx.x;   // 64 threads
  int base = 0;
  int* lp = list + p * G_;
  for (int g0 = 0; g0 < G_; g0 += 64) {
    int g = g0 + lane;
    bool act = (g < G_) && (gene_mask[(size_t)g * P_ + p] != 0.0f);
    unsigned long long bal = __ballot(act);
    int rank = __popcll(bal & ((1ull << lane) - 1ull));
    if (act) lp[base + rank] = g;
    base += __popcll(bal);
  }
  if (lane == 0) cnt[p] = base;
}

// ---------------------------------------------------------------------------
// K1: gate MLP + top-3 + sigmoid. One block (512 thr) per sample.
// hidden[j] computed as 4 g-slices (latency hiding) then reduced.
// Writes gate_weights rows of d_out and the (pathway, weight) selections.
// ---------------------------------------------------------------------------
__global__ __launch_bounds__(512) void k_gate(const float* __restrict__ x_rna,
                                              const float* __restrict__ gw1,
                                              const float* __restrict__ gb1,
                                              const float* __restrict__ gw2,
                                              const float* __restrict__ gb2,
                                              float* __restrict__ out_gw,
                                              int* __restrict__ sel_idx,
                                              float* __restrict__ sel_w) {
  int b = blockIdx.x;
  int t = threadIdx.x;       // 0..511
  int j = t & 127;           // hidden / logit unit
  int slice = t >> 7;        // 0..3 g-slice

  __shared__ float xs[G_];          // 16 KB
  __shared__ float part[4][GH_];
  __shared__ float hid[GH_];
  __shared__ float logitS[P_];
  __shared__ int   s_idx[K_];
  __shared__ float s_val[K_];

  for (int g = t; g < G_; g += 512) xs[g] = x_rna[(size_t)b * G_ + g];
  __syncthreads();

  float acc = 0.f;
  int g0 = slice * (G_ / 4), g1 = g0 + (G_ / 4);
  for (int g = g0; g < g1; ++g) acc = fmaf(xs[g], gw1[(size_t)g * GH_ + j], acc);
  part[slice][j] = acc;
  __syncthreads();

  if (t < GH_) {
    float h = part[0][t] + part[1][t] + part[2][t] + part[3][t] + gb1[t];
    hid[t] = fmaxf(h, 0.f);
  }
  __syncthreads();

  if (t < P_) {
    float acc2 = gb2[t];
    for (int jj = 0; jj < GH_; ++jj) acc2 = fmaf(hid[jj], gw2[(size_t)jj * P_ + t], acc2);
    logitS[t] = acc2;
  }
  __syncthreads();

  if (t == 0) {
    int idxs[K_];
    for (int k = 0; k < K_; ++k) {
      float best = -INFINITY; int bi = 0;
      for (int p = 0; p < P_; ++p) {
        bool taken = false;
        for (int kk = 0; kk < k; ++kk) if (idxs[kk] == p) taken = true;
        if (!taken && logitS[p] > best) { best = logitS[p]; bi = p; }
      }
      idxs[k] = bi;
      float w = 1.f / (1.f + expf(-best));
      s_idx[k] = bi; s_val[k] = w;
      sel_idx[b * K_ + k] = bi;
      sel_w[b * K_ + k] = w;
    }
  }
  __syncthreads();

  if (t < P_) {
    float gwv = 0.f;
    for (int k = 0; k < K_; ++k) if (s_idx[k] == t) gwv = s_val[k];
    out_gw[(size_t)b * P_ + t] = gwv;
  }
}

// ---------------------------------------------------------------------------
// K2: expert compute for each selected (sample, pathway). One wave per
// (b,k); thread h owns hidden unit h. Only mask-active W1 rows are read
// (~10% of D), gathered via the precomputed gene list — coalesced 256 B
// per row. Then BN(eval)+ReLU, then H->O projection via LDS.
// Unweighted expert output stored to eo[b,k,:].
// ---------------------------------------------------------------------------
__global__ __launch_bounds__(64) void k_expert(const float* __restrict__ xr,
                                               const float* __restrict__ xc,
                                               const float* __restrict__ xm,
                                               const float* __restrict__ W1,
                                               const float* __restrict__ b1,
                                               const float* __restrict__ bn_g,
                                               const float* __restrict__ bn_b,
                                               const float* __restrict__ bn_m,
                                               const float* __restrict__ bn_v,
                                               const float* __restrict__ W2,
                                               const float* __restrict__ b2,
                                               const int* __restrict__ cnt,
                                               const int* __restrict__ list,
                                               const int* __restrict__ sel_idx,
                                               float* __restrict__ eo) {
  int bk = blockIdx.x;            // 768 blocks
  int b = bk / K_;
  int h = threadIdx.x;            // 64 threads
  int p = sel_idx[bk];
  int n = cnt[p];
  const int* lp = list + p * G_;
  const float* W1p = W1 + (size_t)p * D_ * H_;
  const float* xrb = xr + (size_t)b * G_;
  const float* xcb = xc + (size_t)b * G_;
  const float* xmb = xm + (size_t)b * G_;

  float acc = 0.f;
  for (int i = 0; i < n; ++i) {
    int g = lp[i];
    float a0 = xrb[g], a1 = xcb[g], a2 = xmb[g];
    acc = fmaf(a0, W1p[((size_t)(0 * G_ + g)) * H_ + h], acc);
    acc = fmaf(a1, W1p[((size_t)(1 * G_ + g)) * H_ + h], acc);
    acc = fmaf(a2, W1p[((size_t)(2 * G_ + g)) * H_ + h], acc);
  }
  int ph = p * H_ + h;
  acc += b1[ph];
  float hn = (acc - bn_m[ph]) * (bn_g[ph] * rsqrtf(bn_v[ph] + EPS_)) + bn_b[ph];
  hn = fmaxf(hn, 0.f);

  __shared__ float hs[H_];
  hs[h] = hn;
  __syncthreads();

  if (h < O_) {
    const float* W2p = W2 + (size_t)p * H_ * O_;
    float o = b2[p * O_ + h];
    for (int jj = 0; jj < H_; ++jj) o = fmaf(hs[jj], W2p[jj * O_ + h], o);
    eo[(size_t)bk * O_ + h] = o;
  }
}

// ---------------------------------------------------------------------------
// K3: weighted combine of the K expert outputs + classifier MLP.
// One thread per sample (deterministic sum over exactly K terms).
// ---------------------------------------------------------------------------
__global__ __launch_bounds__(64) void k_final(const float* __restrict__ eo,
                                              const float* __restrict__ sel_w,
                                              const float* __restrict__ cw1,
                                              const float* __restrict__ cb1,
                                              const float* __restrict__ cw2,
                                              const float* __restrict__ cb2,
                                              float* __restrict__ out_logits) {
  int b = blockIdx.x * blockDim.x + threadIdx.x;
  if (b >= B_) return;
  float feat[O_];
  float w0 = sel_w[b * K_ + 0], w1 = sel_w[b * K_ + 1], w2 = sel_w[b * K_ + 2];
  const float* e0 = eo + (size_t)(b * K_ + 0) * O_;
  const float* e1 = eo + (size_t)(b * K_ + 1) * O_;
  const float* e2 = eo + (size_t)(b * K_ + 2) * O_;
  for (int o = 0; o < O_; ++o)
    feat[o] = w0 * e0[o] + w1 * e1[o] + w2 * e2[o];

  float ch[CH_];
  for (int jj = 0; jj < CH_; ++jj) {
    float a = cb1[jj];
    for (int o = 0; o < O_; ++o) a = fmaf(feat[o], cw1[o * CH_ + jj], a);
    ch[jj] = fmaxf(a, 0.f);
  }
  for (int c = 0; c < C_; ++c) {
    float a = cb2[c];
    for (int jj = 0; jj < CH_; ++jj) a = fmaf(ch[jj], cw2[jj * C_ + c], a);
    out_logits[(size_t)b * C_ + c] = a;
  }
}

// ---------------------------------------------------------------------------
extern "C" void kernel_launch(void* const* d_in, const int* in_sizes, int n_in,
                              void* d_out, int out_size, void* d_ws, size_t ws_size,
                              hipStream_t stream) {
  const float* x_rna    = (const float*)d_in[0];
  const float* x_cnv    = (const float*)d_in[1];
  const float* x_met    = (const float*)d_in[2];
  const float* gene_mask= (const float*)d_in[3];
  const float* gate_w1  = (const float*)d_in[4];
  const float* gate_b1  = (const float*)d_in[5];
  const float* gate_w2  = (const float*)d_in[6];
  const float* gate_b2  = (const float*)d_in[7];
  const float* W1       = (const float*)d_in[8];
  const float* b1       = (const float*)d_in[9];
  const float* bn_g     = (const float*)d_in[10];
  const float* bn_b     = (const float*)d_in[11];
  const float* bn_m     = (const float*)d_in[12];
  const float* bn_v     = (const float*)d_in[13];
  const float* W2       = (const float*)d_in[14];
  const float* b2       = (const float*)d_in[15];
  const float* cls_w1   = (const float*)d_in[16];
  const float* cls_b1   = (const float*)d_in[17];
  const float* cls_w2   = (const float*)d_in[18];
  const float* cls_b2   = (const float*)d_in[19];

  float* out_logits = (float*)d_out;                 // [B, C]
  float* out_gw     = (float*)d_out + (size_t)B_ * C_; // [B, P]

  // workspace layout
  char* ws = (char*)d_ws;
  int*   cnt     = (int*)ws;                                   // 128
  int*   list    = (int*)(ws + 512);                           // 128*4000
  int*   sel_idx = (int*)(ws + 512 + (size_t)P_ * G_ * 4);     // 768
  float* sel_w   = (float*)(ws + 512 + (size_t)P_ * G_ * 4 + 3072);
  float* eo      = (float*)(ws + 512 + (size_t)P_ * G_ * 4 + 6144); // 768*16

  hipLaunchKernelGGL(k_active, dim3(P_), dim3(64), 0, stream,
                     gene_mask, cnt, list);
  hipLaunchKernelGGL(k_gate, dim3(B_), dim3(512), 0, stream,
                     x_rna, gate_w1, gate_b1, gate_w2, gate_b2,
                     out_gw, sel_idx, sel_w);
  hipLaunchKernelGGL(k_expert, dim3(B_ * K_), dim3(64), 0, stream,
                     x_rna, x_cnv, x_met, W1, b1, bn_g, bn_b, bn_m, bn_v,
                     W2, b2, cnt, list, sel_idx, eo);
  hipLaunchKernelGGL(k_final, dim3((B_ + 63) / 64), dim3(64), 0, stream,
                     eo, sel_w, cls_w1, cls_b1, cls_w2, cls_b2, out_logits);
}

// Round 2
// 95.757 us; speedup vs baseline: 2.6610x; 2.6610x over previous
//
#include <hip/hip_runtime.h>
#include <math.h>

#define B_ 256
#define G_ 4000
#define P_ 128
#define D_ 12000
#define H_ 64
#define O_ 16
#define GH_ 128
#define CH_ 8
#define C_ 5
#define K_ 3
#define EPS_ 1e-5f
#define TILE_ 1024

// ---------------------------------------------------------------------------
// K_pre: grid-fused preprocessing.
//   blocks [0,128):    per-pathway active-gene compaction (8 waves, 2-pass)
//   blocks [128,384):  gate MLP + top-3 + sigmoid (one block per sample)
// ---------------------------------------------------------------------------
__global__ __launch_bounds__(512) void k_pre(const float* __restrict__ gene_mask,
                                             const float* __restrict__ x_rna,
                                             const float* __restrict__ gw1,
                                             const float* __restrict__ gb1,
                                             const float* __restrict__ gw2,
                                             const float* __restrict__ gb2,
                                             int* __restrict__ cnt,
                                             int* __restrict__ list,
                                             float* __restrict__ out_gw,
                                             int* __restrict__ sel_idx,
                                             float* __restrict__ sel_w) {
  int t = threadIdx.x;

  if (blockIdx.x < P_) {
    // ---- active-gene compaction, pathway p, 8 waves ----
    int p = blockIdx.x;
    int lane = t & 63;
    int w = t >> 6;                 // 0..7
    __shared__ int wcnt[8];
    int* lp = list + (size_t)p * G_;
    const int per = (G_ + 7) / 8;   // 500
    int start = w * per;
    int end = start + per; if (end > G_) end = G_;

    int count = 0;
    for (int g0 = start; g0 < end; g0 += 64) {
      int g = g0 + lane;
      bool act = (g < end) && (gene_mask[(size_t)g * P_ + p] != 0.0f);
      count += __popcll(__ballot(act));
    }
    if (lane == 0) wcnt[w] = count;
    __syncthreads();
    if (t == 0) {
      int tot = 0;
      for (int i = 0; i < 8; ++i) tot += wcnt[i];
      cnt[p] = tot;
    }
    int base = 0;
    for (int i = 0; i < w; ++i) base += wcnt[i];
    for (int g0 = start; g0 < end; g0 += 64) {
      int g = g0 + lane;
      bool act = (g < end) && (gene_mask[(size_t)g * P_ + p] != 0.0f);
      unsigned long long bal = __ballot(act);
      int rank = __popcll(bal & ((1ull << lane) - 1ull));
      if (act) lp[base + rank] = g;
      base += __popcll(bal);
    }
    return;
  }

  // ---- gate MLP for sample b ----
  int b = blockIdx.x - P_;
  int j = t & 127;                  // hidden / logit unit
  int slice = t >> 7;               // 0..3 g-slice

  __shared__ float xs[G_];          // 16 KB
  __shared__ float part[4][GH_];
  __shared__ float hid[GH_];
  __shared__ float logitS[P_];
  __shared__ int   s_idx[K_];
  __shared__ float s_val[K_];

  for (int g = t; g < G_; g += 512) xs[g] = x_rna[(size_t)b * G_ + g];
  __syncthreads();

  float acc = 0.f;
  int g0 = slice * (G_ / 4), g1 = g0 + (G_ / 4);
  for (int g = g0; g < g1; ++g) acc = fmaf(xs[g], gw1[(size_t)g * GH_ + j], acc);
  part[slice][j] = acc;
  __syncthreads();

  if (t < GH_) {
    float h = part[0][t] + part[1][t] + part[2][t] + part[3][t] + gb1[t];
    hid[t] = fmaxf(h, 0.f);
  }
  __syncthreads();

  if (t < P_) {
    float acc2 = gb2[t];
    for (int jj = 0; jj < GH_; ++jj) acc2 = fmaf(hid[jj], gw2[(size_t)jj * P_ + t], acc2);
    logitS[t] = acc2;
  }
  __syncthreads();

  if (t == 0) {
    int idxs[K_];
    for (int k = 0; k < K_; ++k) {
      float best = -INFINITY; int bi = 0;
      for (int p = 0; p < P_; ++p) {
        bool taken = false;
        for (int kk = 0; kk < k; ++kk) if (idxs[kk] == p) taken = true;
        if (!taken && logitS[p] > best) { best = logitS[p]; bi = p; }
      }
      idxs[k] = bi;
      float w = 1.f / (1.f + expf(-best));
      s_idx[k] = bi; s_val[k] = w;
      sel_idx[b * K_ + k] = bi;
      sel_w[b * K_ + k] = w;
    }
  }
  __syncthreads();

  if (t < P_) {
    float gwv = 0.f;
    for (int k = 0; k < K_; ++k) if (s_idx[k] == t) gwv = s_val[k];
    out_gw[(size_t)b * P_ + t] = gwv;
  }
}

// ---------------------------------------------------------------------------
// K2: expert compute, one block (8 waves) per selected (sample, pathway).
// Gene list + gathered x staged in LDS; each wave strides the gene list with
// 3 independent accumulators; LDS tree-reduce; BN+ReLU; H->O projection.
// ---------------------------------------------------------------------------
__global__ __launch_bounds__(512) void k_expert(const float* __restrict__ xr,
                                                const float* __restrict__ xc,
                                                const float* __restrict__ xm,
                                                const float* __restrict__ W1,
                                                const float* __restrict__ b1,
                                                const float* __restrict__ bn_g,
                                                const float* __restrict__ bn_b,
                                                const float* __restrict__ bn_m,
                                                const float* __restrict__ bn_v,
                                                const float* __restrict__ W2,
                                                const float* __restrict__ b2,
                                                const int* __restrict__ cnt,
                                                const int* __restrict__ list,
                                                const int* __restrict__ sel_idx,
                                                float* __restrict__ eo) {
  int bk = blockIdx.x;              // 768 blocks
  int b = bk / K_;
  int t = threadIdx.x;
  int h = t & 63;
  int w = t >> 6;                   // 0..7
  int p = sel_idx[bk];
  int n = cnt[p];
  const int* lp = list + (size_t)p * G_;
  const float* W1p = W1 + (size_t)p * D_ * H_;
  const float* xrb = xr + (size_t)b * G_;
  const float* xcb = xc + (size_t)b * G_;
  const float* xmb = xm + (size_t)b * G_;

  __shared__ int   glist[TILE_];
  __shared__ float xv0[TILE_], xv1[TILE_], xv2[TILE_];
  __shared__ float part[8][H_];
  __shared__ float hs[H_];

  float acc0 = 0.f, acc1 = 0.f, acc2 = 0.f;
  for (int t0 = 0; t0 < n; t0 += TILE_) {
    int m = n - t0; if (m > TILE_) m = TILE_;
    __syncthreads();
    for (int i = t; i < m; i += 512) {
      int g = lp[t0 + i];
      glist[i] = g;
      xv0[i] = xrb[g]; xv1[i] = xcb[g]; xv2[i] = xmb[g];
    }
    __syncthreads();
    for (int i = w; i < m; i += 8) {
      int g = glist[i];
      const float* r = W1p + (size_t)g * H_ + h;
      acc0 = fmaf(xv0[i], r[0], acc0);
      acc1 = fmaf(xv1[i], r[(size_t)G_ * H_], acc1);
      acc2 = fmaf(xv2[i], r[(size_t)(2 * G_) * H_], acc2);
    }
  }
  part[w][h] = acc0 + acc1 + acc2;
  __syncthreads();

  if (t < H_) {
    float s = part[0][t] + part[1][t] + part[2][t] + part[3][t] +
              part[4][t] + part[5][t] + part[6][t] + part[7][t];
    int ph = p * H_ + t;
    s += b1[ph];
    float hn = (s - bn_m[ph]) * (bn_g[ph] * rsqrtf(bn_v[ph] + EPS_)) + bn_b[ph];
    hs[t] = fmaxf(hn, 0.f);
  }
  __syncthreads();

  if (t < O_) {
    const float* W2p = W2 + (size_t)p * H_ * O_;
    float o = b2[p * O_ + t];
    for (int jj = 0; jj < H_; ++jj) o = fmaf(hs[jj], W2p[jj * O_ + t], o);
    eo[(size_t)bk * O_ + t] = o;
  }
}

// ---------------------------------------------------------------------------
// K3: weighted combine of the K expert outputs + classifier MLP.
// ---------------------------------------------------------------------------
__global__ __launch_bounds__(64) void k_final(const float* __restrict__ eo,
                                              const float* __restrict__ sel_w,
                                              const float* __restrict__ cw1,
                                              const float* __restrict__ cb1,
                                              const float* __restrict__ cw2,
                                              const float* __restrict__ cb2,
                                              float* __restrict__ out_logits) {
  int b = blockIdx.x * blockDim.x + threadIdx.x;
  if (b >= B_) return;
  float feat[O_];
  float w0 = sel_w[b * K_ + 0], w1 = sel_w[b * K_ + 1], w2 = sel_w[b * K_ + 2];
  const float* e0 = eo + (size_t)(b * K_ + 0) * O_;
  const float* e1 = eo + (size_t)(b * K_ + 1) * O_;
  const float* e2 = eo + (size_t)(b * K_ + 2) * O_;
  for (int o = 0; o < O_; ++o)
    feat[o] = w0 * e0[o] + w1 * e1[o] + w2 * e2[o];

  float ch[CH_];
  for (int jj = 0; jj < CH_; ++jj) {
    float a = cb1[jj];
    for (int o = 0; o < O_; ++o) a = fmaf(feat[o], cw1[o * CH_ + jj], a);
    ch[jj] = fmaxf(a, 0.f);
  }
  for (int c = 0; c < C_; ++c) {
    float a = cb2[c];
    for (int jj = 0; jj < CH_; ++jj) a = fmaf(ch[jj], cw2[jj * C_ + c], a);
    out_logits[(size_t)b * C_ + c] = a;
  }
}

// ---------------------------------------------------------------------------
extern "C" void kernel_launch(void* const* d_in, const int* in_sizes, int n_in,
                              void* d_out, int out_size, void* d_ws, size_t ws_size,
                              hipStream_t stream) {
  const float* x_rna    = (const float*)d_in[0];
  const float* x_cnv    = (const float*)d_in[1];
  const float* x_met    = (const float*)d_in[2];
  const float* gene_mask= (const float*)d_in[3];
  const float* gate_w1  = (const float*)d_in[4];
  const float* gate_b1  = (const float*)d_in[5];
  const float* gate_w2  = (const float*)d_in[6];
  const float* gate_b2  = (const float*)d_in[7];
  const float* W1       = (const float*)d_in[8];
  const float* b1       = (const float*)d_in[9];
  const float* bn_g     = (const float*)d_in[10];
  const float* bn_b     = (const float*)d_in[11];
  const float* bn_m     = (const float*)d_in[12];
  const float* bn_v     = (const float*)d_in[13];
  const float* W2       = (const float*)d_in[14];
  const float* b2       = (const float*)d_in[15];
  const float* cls_w1   = (const float*)d_in[16];
  const float* cls_b1   = (const float*)d_in[17];
  const float* cls_w2   = (const float*)d_in[18];
  const float* cls_b2   = (const float*)d_in[19];

  float* out_logits = (float*)d_out;                   // [B, C]
  float* out_gw     = (float*)d_out + (size_t)B_ * C_; // [B, P]

  // workspace layout
  char* ws = (char*)d_ws;
  int*   cnt     = (int*)ws;                                   // 128
  int*   list    = (int*)(ws + 512);                           // 128*4000
  int*   sel_idx = (int*)(ws + 512 + (size_t)P_ * G_ * 4);     // 768
  float* sel_w   = (float*)(ws + 512 + (size_t)P_ * G_ * 4 + 3072);
  float* eo      = (float*)(ws + 512 + (size_t)P_ * G_ * 4 + 6144); // 768*16

  hipLaunchKernelGGL(k_pre, dim3(P_ + B_), dim3(512), 0, stream,
                     gene_mask, x_rna, gate_w1, gate_b1, gate_w2, gate_b2,
                     cnt, list, out_gw, sel_idx, sel_w);
  hipLaunchKernelGGL(k_expert, dim3(B_ * K_), dim3(512), 0, stream,
                     x_rna, x_cnv, x_met, W1, b1, bn_g, bn_b, bn_m, bn_v,
                     W2, b2, cnt, list, sel_idx, eo);
  hipLaunchKernelGGL(k_final, dim3((B_ + 63) / 64), dim3(64), 0, stream,
                     eo, sel_w, cls_w1, cls_b1, cls_w2, cls_b2, out_logits);
}